// Round 19
// baseline (197.476 us; speedup 1.0000x reference)
//
#include <hip/hip_runtime.h>

#define N_NODES 50000
#define E_EDGES 800000
#define IN_DIM  256
#define HID     128
#define HALF    64
#define OUT_DIM 2
#define NW      32               // nodes per block tile
#define SLOPE   0.01f

#define ST      132              // tile row stride (fp32/uint32 units)
#define WSLICE  (NW * ST)        // 4224 words = 16.9 KB

#define SSTRIDE 520              // bf16 units per s-step in A planes (512+8 pad)
#define PLANE   (8 * SSTRIDE)    // 4160 bf16 per plane

#define SCAN_B  512
#define SCAN_NB ((N_NODES + SCAN_B - 1) / SCAN_B)   // 98

typedef unsigned int uint32;
typedef __attribute__((ext_vector_type(8)))  __bf16 bf16x8v;
typedef __attribute__((ext_vector_type(16))) float  f32x16;

union BF8 { bf16x8v v; unsigned short s[8]; uint4 q; };

// weight-fragment table offsets (frag = 2 uint4: hi, lo)
#define FI_F 0        // W_in : S=16 -> 4096 frags
#define FN_F 4096     // W_nor: S=4  -> 1024
#define FA_F 5120     // W_abnor: S=4 -> 1024
#define FT_F 6144     // W_att: S=8 -> 2048
#define FU_F 8192     // W_upd: S=8 -> 2048
#define F_TOTAL 10240 // 20480 uint4 = 320 KB

__device__ __forceinline__ uint32 rne16u(uint32 u) {
    return (u + 0x7fffu + ((u >> 16) & 1u)) >> 16;
}

// pack one fp32 into (hi_bf16 << 16) | lo_bf16  (error-compensated split)
__device__ __forceinline__ uint32 pack_hl(float v) {
    uint32 uu = __float_as_uint(v);
    uint32 hh = rne16u(uu);
    float  fh = __uint_as_float(hh << 16);
    float  r  = v - fh;
    uint32 ll = rne16u(__float_as_uint(r));
    return (hh << 16) | ll;
}

// fast tanh / sigmoid via v_exp + v_rcp (~1e-7 rel err)
__device__ __forceinline__ float fast_tanh(float x) {
    float ex = __expf(2.f * x);
    return 1.f - 2.f * __builtin_amdgcn_rcpf(ex + 1.f);
}
__device__ __forceinline__ float fast_sig(float x) {
    return __builtin_amdgcn_rcpf(1.f + __expf(-x));
}

__device__ __forceinline__ void mfma3(f32x16& acc, bf16x8v ah, bf16x8v al,
                                      bf16x8v bh, bf16x8v bl) {
    acc = __builtin_amdgcn_mfma_f32_32x32x16_bf16(ah, bh, acc, 0, 0, 0);
    acc = __builtin_amdgcn_mfma_f32_32x32x16_bf16(ah, bl, acc, 0, 0, 0);
    acc = __builtin_amdgcn_mfma_f32_32x32x16_bf16(al, bh, acc, 0, 0, 0);
}

// split a float4 at (row rr, local col k) into fragment-ordered LDS planes.
// A-frag (32x32x16): slot = s*SSTRIDE + lane*8 + j, lane = rr + 32*((k>>3)&1).
__device__ __forceinline__ void stage_split4(__bf16* __restrict__ Ahi,
                                             __bf16* __restrict__ Alo,
                                             int rr, int k, float4 v) {
    int s_idx = k >> 4, jb = k & 7, lt = rr + 32 * ((k >> 3) & 1);
    int base = s_idx * SSTRIDE + lt * 8 + jb;
    float f[4] = {v.x, v.y, v.z, v.w};
    uint32 h[4], lo[4];
    #pragma unroll
    for (int j = 0; j < 4; j++) {
        uint32 uu = __float_as_uint(f[j]);
        uint32 hh = rne16u(uu);
        float  fh = __uint_as_float(hh << 16);
        float  r  = f[j] - fh;
        h[j] = hh; lo[j] = rne16u(__float_as_uint(r));
    }
    *(uint2*)(Ahi + base) = make_uint2(h[0] | (h[1] << 16), h[2] | (h[3] << 16));
    *(uint2*)(Alo + base) = make_uint2(lo[0] | (lo[1] << 16), lo[2] | (lo[3] << 16));
}

// 1-tile GEMM from pre-split planes: pure ds_read + F-load + MFMA
__device__ __forceinline__ void mfma_gemm1_pre(f32x16& acc,
        const __bf16* __restrict__ Ahi, const __bf16* __restrict__ Alo,
        int S, int sg0, const uint4* __restrict__ F, int fbase, int l, int t) {
    for (int s = 0; s < S; s++) {
        bf16x8v ah = *(const bf16x8v*)&Ahi[s * SSTRIDE + l * 8];
        bf16x8v al = *(const bf16x8v*)&Alo[s * SSTRIDE + l * 8];
        int f = fbase + ((sg0 + s) * 4 + t) * 64 + l;
        BF8 bh, bl; bh.q = F[2 * f]; bl.q = F[2 * f + 1];
        mfma3(acc, ah, al, bh.v, bl.v);
    }
}

// 1-tile GEMM from packed (hi|lo) uint32 tile: 2 b128 + 8 shift/mask unpacks
__device__ __forceinline__ void mfma_gemm1_pk(f32x16& acc, const uint32* T,
        int aoff, int S, const uint4* __restrict__ F, int fbase, int l, int t) {
    const int row = l & 31, khi = 8 * (l >> 5);
    for (int s = 0; s < S; s++) {
        int k0 = aoff + 16 * s + khi;
        uint4 qa = *(const uint4*)&T[row * ST + k0];
        uint4 qb = *(const uint4*)&T[row * ST + k0 + 4];
        BF8 ah, al;
        ah.q.x = (qa.x >> 16) | (qa.y & 0xffff0000u);
        ah.q.y = (qa.z >> 16) | (qa.w & 0xffff0000u);
        ah.q.z = (qb.x >> 16) | (qb.y & 0xffff0000u);
        ah.q.w = (qb.z >> 16) | (qb.w & 0xffff0000u);
        al.q.x = (qa.x & 0xffffu) | (qa.y << 16);
        al.q.y = (qa.z & 0xffffu) | (qa.w << 16);
        al.q.z = (qb.x & 0xffffu) | (qb.y << 16);
        al.q.w = (qb.z & 0xffffu) | (qb.w << 16);
        int f = fbase + (s * 4 + t) * 64 + l;
        BF8 bh, bl; bh.q = F[2 * f]; bl.q = F[2 * f + 1];
        mfma3(acc, ah.v, al.v, bh.v, bl.v);
    }
}

__device__ __forceinline__ uint32 pack_bf2(float x, float y) {
    return rne16u(__float_as_uint(x)) | (rne16u(__float_as_uint(y)) << 16);
}

// ---------------------------------------------------------------- degree ----
__global__ void zero_int_kernel(int* __restrict__ p, int n) {
    int i = blockIdx.x * blockDim.x + threadIdx.x;
    if (i < n) p[i] = 0;
}

__global__ void deg_ticket_kernel(const int* __restrict__ col,
                                  int* __restrict__ cnt, int* __restrict__ ticket) {
    int e = blockIdx.x * blockDim.x + threadIdx.x;
    if (e < E_EDGES) ticket[e] = atomicAdd(&cnt[col[e]], 1);
}

// ------------------------------------------------------- 3-pass fast scan ---
__device__ __forceinline__ int wave_iscan(int v, int l) {
    #pragma unroll
    for (int off = 1; off < 64; off <<= 1) {
        int t = __shfl_up(v, off, 64);
        if (l >= off) v += t;
    }
    return v;
}

__global__ __launch_bounds__(SCAN_B) void scan1_kernel(
    const int* __restrict__ cnt, int* __restrict__ row_start, int* __restrict__ bsum)
{
    __shared__ int wsum[SCAN_B / 64];
    int i = blockIdx.x * SCAN_B + threadIdx.x;
    int v = (i < N_NODES) ? cnt[i] : 0;
    int l = threadIdx.x & 63, w = threadIdx.x >> 6;
    int isc = wave_iscan(v, l);
    if (l == 63) wsum[w] = isc;
    __syncthreads();
    int wo = 0;
    #pragma unroll
    for (int k = 0; k < SCAN_B / 64; k++) wo += (k < w) ? wsum[k] : 0;
    if (i < N_NODES) row_start[i] = wo + isc - v;
    if (threadIdx.x == SCAN_B - 1) bsum[blockIdx.x] = wo + isc;
}

__global__ __launch_bounds__(128) void scan2_kernel(
    int* __restrict__ bsum, int* __restrict__ row_start)
{
    __shared__ int wsum[2];
    int i = threadIdx.x;
    int v = (i < SCAN_NB) ? bsum[i] : 0;
    int l = i & 63, w = i >> 6;
    int isc = wave_iscan(v, l);
    if (l == 63) wsum[w] = isc;
    __syncthreads();
    int wo = (w == 1) ? wsum[0] : 0;
    if (i < SCAN_NB) bsum[i] = wo + isc - v;
    if (i == SCAN_NB - 1) row_start[N_NODES] = wo + isc;
}

__global__ __launch_bounds__(SCAN_B) void scan3_kernel(
    const int* __restrict__ bsum, int* __restrict__ row_start)
{
    int i = blockIdx.x * SCAN_B + threadIdx.x;
    if (i < N_NODES) row_start[i] += bsum[blockIdx.x];
}

__global__ void fill_kernel(const int* __restrict__ ei,
                            const int* __restrict__ row_start,
                            const int* __restrict__ ticket,
                            int* __restrict__ csr_src)
{
    int e = blockIdx.x * blockDim.x + threadIdx.x;
    if (e >= E_EDGES) return;
    int j = ei[e];
    int i = ei[E_EDGES + e];
    csr_src[row_start[i] + ticket[e]] = j;
}

// ---------------------------------------------------- weight prep (split) ---
// B-frag layout (32x32x16): col = lane&31, k = 8*(lane>>5)+j.
__global__ __launch_bounds__(256) void prep_w_kernel(
    const float* __restrict__ W_in, const float* __restrict__ W_nor,
    const float* __restrict__ W_ab, const float* __restrict__ W_att,
    const float* __restrict__ W_upd,
    uint4* __restrict__ F)
{
    int idx = blockIdx.x * 256 + threadIdx.x;
    const float* W; int fbase, fi;
    if (idx < 4096)       { W = W_in;  fbase = FI_F; fi = idx; }
    else if (idx < 5120)  { W = W_nor; fbase = FN_F; fi = idx - 4096; }
    else if (idx < 6144)  { W = W_ab;  fbase = FA_F; fi = idx - 5120; }
    else if (idx < 8192)  { W = W_att; fbase = FT_F; fi = idx - 6144; }
    else if (idx < 10240) { W = W_upd; fbase = FU_F; fi = idx - 8192; }
    else return;
    int l = fi & 63, st = fi >> 6, t = st & 3, s = st >> 2;
    int k0 = 16 * s + 8 * (l >> 5);
    int c  = 32 * t + (l & 31);
    uint32 hi[8], lo[8];
    #pragma unroll
    for (int j = 0; j < 8; j++) {
        float v = W[(size_t)(k0 + j) * HID + c];
        uint32 uu = __float_as_uint(v);
        uint32 h  = rne16u(uu);
        float  fh = __uint_as_float(h << 16);
        float  r  = v - fh;
        hi[j] = h;
        lo[j] = rne16u(__float_as_uint(r));
    }
    uint4 H, L;
    H.x = hi[0] | (hi[1] << 16); H.y = hi[2] | (hi[3] << 16);
    H.z = hi[4] | (hi[5] << 16); H.w = hi[6] | (hi[7] << 16);
    L.x = lo[0] | (lo[1] << 16); L.y = lo[2] | (lo[3] << 16);
    L.z = lo[4] | (lo[5] << 16); L.w = lo[6] | (lo[7] << 16);
    int f = fbase + fi;
    F[2 * f]     = H;
    F[2 * f + 1] = L;
}

// ------------------------------------------------------------- node phase ---
// 256 threads = 4 waves per 32-node tile; wave w owns output cols 32w..32w+31.
__global__ __launch_bounds__(256, 6) void node_phase_kernel(
    const float* __restrict__ x,
    const float* __restrict__ b_in,  const float* __restrict__ b_nor,
    const float* __restrict__ b_abnor, const float* __restrict__ b_att,
    const float* __restrict__ v_att,
    const int* __restrict__ cnt,
    const uint4* __restrict__ F,
    uint32* __restrict__ u)            // [N][HID/2] packed bf16 pairs
{
    __shared__ __align__(16) float smem[WSLICE];   // 16.9 KB overlaid
    __shared__ float dinvs[NW];
    __shared__ float gpart[4][NW];
    __bf16* Ahi = (__bf16*)smem;              // padded plane (4160 bf16)
    __bf16* Alo = (__bf16*)smem + PLANE;      // second plane
    uint32* T   = (uint32*)smem;              // packed h/s tile [32][ST]

    const int tid    = threadIdx.x;
    const int w      = tid >> 6;          // tile t = w
    const int l      = tid & 63;
    const int col    = l & 31;
    const int hi     = l >> 5;
    const int wnode0 = blockIdx.x * NW;

    if (tid < NW) {
        int nd = wnode0 + tid;
        float c = (nd < N_NODES) ? (float)cnt[nd] : 0.f;
        dinvs[tid] = rsqrtf(c + 1.0f);
    }

    // ---- h = leaky_relu(x @ W_in + b_in), K=256 in two 128-halves ----
    f32x16 hacc;
    {
        float bv = b_in[32 * w + col];
        #pragma unroll
        for (int r2 = 0; r2 < 16; r2++) hacc[r2] = bv;
    }
    for (int half = 0; half < 2; half++) {
        #pragma unroll
        for (int it = 0; it < 4; it++) {           // 1024 float4 over 256 thr
            int i = it * 256 + tid;
            int rr = i >> 5, kq = i & 31, k = 4 * kq;
            int nd = wnode0 + rr; if (nd >= N_NODES) nd = N_NODES - 1;
            float4 v = *(const float4*)(x + (size_t)nd * IN_DIM + half * 128 + k);
            stage_split4(Ahi, Alo, rr, k, v);
        }
        __syncthreads();
        mfma_gemm1_pre(hacc, Ahi, Alo, 8, half * 8, F, FI_F, l, w);
        __syncthreads();   // planes consumed; safe to overwrite
    }

    // ---- lrelu(h) -> packed tile cols [32w, 32w+32) ----
    #pragma unroll
    for (int rg = 0; rg < 16; rg++) {
        int rrow = (rg & 3) + 8 * (rg >> 2) + 4 * hi;
        float v = hacc[rg];
        v = v > 0.f ? v : SLOPE * v;
        T[rrow * ST + 32 * w + col] = pack_hl(v);
    }
    __syncthreads();

    // ---- xn = h[:, :64] @ W_nor ; xa = h[:, 64:] @ W_abnor ----
    f32x16 xn, xa;
    {
        float bv = b_nor[32 * w + col];
        #pragma unroll
        for (int r2 = 0; r2 < 16; r2++) xn[r2] = bv;
    }
    mfma_gemm1_pk(xn, T, 0, 4, F, FN_F, l, w);
    {
        float bv = b_abnor[32 * w + col];
        #pragma unroll
        for (int r2 = 0; r2 < 16; r2++) xa[r2] = bv;
    }
    mfma_gemm1_pk(xa, T, HALF, 4, F, FA_F, l, w);
    __syncthreads();   // h consumed

    // ---- s = xn+xa (regs + packed tile); d = xn-xa (regs) ----
    f32x16 sv, d;
    #pragma unroll
    for (int rg = 0; rg < 16; rg++) {
        int rrow = (rg & 3) + 8 * (rg >> 2) + 4 * hi;
        sv[rg] = xn[rg] + xa[rg];
        d[rg]  = xn[rg] - xa[rg];
        T[rrow * ST + 32 * w + col] = pack_hl(sv[rg]);
    }
    __syncthreads();

    // ---- t = s @ W_att + b_att ----
    f32x16 tac;
    {
        float bv = b_att[32 * w + col];
        #pragma unroll
        for (int r2 = 0; r2 < 16; r2++) tac[r2] = bv;
    }
    mfma_gemm1_pk(tac, T, 0, 8, F, FT_F, l, w);

    // ---- alpha: per-wave partial (32 cols), cross-wave via gpart ----
    float g[16];
    {
        float vv = v_att[32 * w + col];
        #pragma unroll
        for (int rg = 0; rg < 16; rg++) g[rg] = fast_tanh(tac[rg]) * vv;
    }
    #pragma unroll
    for (int msk = 16; msk >= 1; msk >>= 1) {
        #pragma unroll
        for (int rg = 0; rg < 16; rg++) g[rg] += __shfl_xor(g[rg], msk, 64);
    }
    if (col == 0) {
        #pragma unroll
        for (int rg = 0; rg < 16; rg++) {
            int rrow = (rg & 3) + 8 * (rg >> 2) + 4 * hi;
            gpart[w][rrow] = g[rg];
        }
    }
    __syncthreads();

    float am[16];
    #pragma unroll
    for (int rg = 0; rg < 16; rg++) {
        int rrow = (rg & 3) + 8 * (rg >> 2) + 4 * hi;
        float gt = gpart[0][rrow] + gpart[1][rrow] + gpart[2][rrow] + gpart[3][rrow];
        am[rg] = fast_sig(gt) - 0.5f;
    }

    // ---- u = dinv * (0.5*s + (alpha-0.5)*d), packed bf16 pairs ----
    #pragma unroll
    for (int rg = 0; rg < 16; rg++) {
        int rrow = (rg & 3) + 8 * (rg >> 2) + 4 * hi;
        int n    = wnode0 + rrow;
        float uv = dinvs[rrow] * (0.5f * sv[rg] + am[rg] * d[rg]);
        float pv = __shfl_xor(uv, 1, 64);
        if (((l & 1) == 0) && n < N_NODES) {
            u[(size_t)n * (HID / 2) + 16 * w + (col >> 1)] = pack_bf2(uv, pv);
        }
    }
}

// ----------------------------------------------- fused gather + final phase ---
// 256 threads = 4 waves per 32-node tile. Wave w gathers nodes 8w..8w+7 from
// u via CSR (serial per node, predicated 8-batches), applies dinv, and stages
// the aggregated rows DIRECTLY into the MFMA A-planes. Then FU MFMA + cls.
// launch_bounds (256,8): kernel fits 32-64 VGPR -> 8 waves/SIMD resident.
__global__ __launch_bounds__(256, 8) void final_fused_kernel(
    const int* __restrict__ row_start, const int* __restrict__ csr_src,
    const uint32* __restrict__ u, const int* __restrict__ cnt,
    const float* __restrict__ b_upd,
    const float* __restrict__ W_cls, const float* __restrict__ b_cls,
    const uint4* __restrict__ F,
    float* __restrict__ out)
{
    __shared__ __align__(16) float smem[WSLICE];
    __bf16* Ahi = (__bf16*)smem;
    __bf16* Alo = (__bf16*)smem + PLANE;

    const int tid    = threadIdx.x;
    const int w      = tid >> 6;
    const int l      = tid & 63;
    const int col    = l & 31;
    const int hi     = l >> 5;
    const int wnode0 = blockIdx.x * NW;

    const size_t RW = HID / 2;
    // plane slot for this lane's pair (cols k=2l, 2l+1); same slot for all 8 rows
    const int kk   = 2 * l;
    const int sidx = kk >> 4, jj = kk & 7, ltb = 32 * ((kk >> 3) & 1);

    for (int q = 0; q < 8; q++) {
        int rr = 8 * w + q;
        int nd = wnode0 + rr; if (nd >= N_NODES) nd = N_NODES - 1;

        uint32 v = u[(size_t)nd * RW + l];
        float sx = __uint_as_float(v << 16);
        float sy = __uint_as_float(v & 0xffff0000u);

        int b = row_start[nd], e = row_start[nd + 1];
        for (int p = b; p < e; p += 8) {
            int idx[8];
            #pragma unroll
            for (int qq = 0; qq < 8; qq++) {
                int a = p + qq; if (a > e - 1) a = e - 1;
                idx[qq] = csr_src[a];
            }
            uint32 vv[8];
            #pragma unroll
            for (int qq = 0; qq < 8; qq++) vv[qq] = u[(size_t)idx[qq] * RW + l];
            #pragma unroll
            for (int qq = 0; qq < 8; qq++) {
                if (p + qq < e) {
                    sx += __uint_as_float(vv[qq] << 16);
                    sy += __uint_as_float(vv[qq] & 0xffff0000u);
                }
            }
        }
        float dv = rsqrtf((float)cnt[nd] + 1.0f);
        sx *= dv; sy *= dv;

        // split-stage this pair into the A-planes
        uint32 px = pack_hl(sx), py = pack_hl(sy);
        int base = sidx * SSTRIDE + (rr + ltb) * 8 + jj;
        *(uint32*)&Ahi[base] = (px >> 16) | (py & 0xffff0000u);
        *(uint32*)&Alo[base] = (px & 0xffffu) | (py << 16);
    }
    __syncthreads();

    f32x16 up;
    {
        float bv = b_upd[32 * w + col];
        #pragma unroll
        for (int r2 = 0; r2 < 16; r2++) up[r2] = bv;
    }
    mfma_gemm1_pre(up, Ahi, Alo, 8, 0, F, FU_F, l, w);
    __syncthreads();   // planes consumed before overwrite

    // lrelu -> fp32 tile cols [32w, 32w+32)
    float* B = smem;
    #pragma unroll
    for (int rg = 0; rg < 16; rg++) {
        int rrow = (rg & 3) + 8 * (rg >> 2) + 4 * hi;
        float v = up[rg];
        B[rrow * ST + 32 * w + col] = v > 0.f ? v : SLOPE * v;
    }
    __syncthreads();

    // classifier: tid = n*8 + o*4 + c ; 4 lanes per (node,out), shfl-reduce
    {
        int n = tid >> 3, o = (tid >> 2) & 1, c = tid & 3;
        float s = 0.f;
        int k0 = c * 32;
        for (int k = k0; k < k0 + 32; k++)
            s = fmaf(B[n * ST + k], W_cls[k * OUT_DIM + o], s);
        s += __shfl_xor(s, 1, 64);
        s += __shfl_xor(s, 2, 64);
        if (c == 0 && wnode0 + n < N_NODES) {
            out[(size_t)(wnode0 + n) * OUT_DIM + o] = s + b_cls[o];
        }
    }
}

// ------------------------------------------------------------------ launch --
extern "C" void kernel_launch(void* const* d_in, const int* in_sizes, int n_in,
                              void* d_out, int out_size, void* d_ws, size_t ws_size,
                              hipStream_t stream)
{
    const float* x       = (const float*)d_in[0];
    const int*   ei      = (const int*)  d_in[1];   // [2, E] int32
    const float* W_in    = (const float*)d_in[2];
    const float* b_in    = (const float*)d_in[3];
    const float* W_nor   = (const float*)d_in[4];
    const float* b_nor   = (const float*)d_in[5];
    const float* W_abnor = (const float*)d_in[6];
    const float* b_abnor = (const float*)d_in[7];
    const float* W_att   = (const float*)d_in[8];
    const float* b_att   = (const float*)d_in[9];
    const float* v_att   = (const float*)d_in[10];
    const float* W_upd   = (const float*)d_in[11];
    const float* b_upd   = (const float*)d_in[12];
    const float* W_cls   = (const float*)d_in[13];
    const float* b_cls   = (const float*)d_in[14];
    float* out = (float*)d_out;

    // ws: cnt[N] | row_start[N+1] | bsum[128] | csr_src[E] | ticket[E]
    //     | u_bf16[N*64 uints] | F[20480 uint4]   (~20 MB)
    char* base = (char*)d_ws;
    int*  cnt       = (int*)base;
    int*  row_start = cnt + N_NODES;
    int*  bsum      = row_start + (N_NODES + 1);
    int*  csr_src   = bsum + 128;
    int*  ticket    = csr_src + E_EDGES;
    size_t off_u    = (((size_t)(2 * N_NODES + 129 + 2 * E_EDGES)) * 4 + 63) & ~(size_t)63;
    uint32* u       = (uint32*)(base + off_u);
    size_t off_f    = (off_u + (size_t)N_NODES * (HID / 2) * 4 + 63) & ~(size_t)63;
    uint4* F        = (uint4*)(base + off_f);

    const int nblk = (N_NODES + NW - 1) / NW;   // 1563

    zero_int_kernel<<<(N_NODES + 255) / 256, 256, 0, stream>>>(cnt, N_NODES);
    deg_ticket_kernel<<<(E_EDGES + 255) / 256, 256, 0, stream>>>(ei + E_EDGES, cnt, ticket);
    scan1_kernel<<<SCAN_NB, SCAN_B, 0, stream>>>(cnt, row_start, bsum);
    scan2_kernel<<<1, 128, 0, stream>>>(bsum, row_start);
    scan3_kernel<<<SCAN_NB, SCAN_B, 0, stream>>>(bsum, row_start);
    fill_kernel<<<(E_EDGES + 255) / 256, 256, 0, stream>>>(ei, row_start, ticket, csr_src);
    prep_w_kernel<<<F_TOTAL / 256, 256, 0, stream>>>(W_in, W_nor, W_abnor, W_att, W_upd, F);
    node_phase_kernel<<<nblk, 256, 0, stream>>>(
        x, b_in, b_nor, b_abnor, b_att, v_att, cnt, F, u);
    final_fused_kernel<<<nblk, 256, 0, stream>>>(
        row_start, csr_src, u, cnt, b_upd, W_cls, b_cls, F, out);
}

// Round 20
// 158.964 us; speedup vs baseline: 1.2423x; 1.2423x over previous
//
#include <hip/hip_runtime.h>

#define N_NODES 50000
#define E_EDGES 800000
#define IN_DIM  256
#define HID     128
#define HALF    64
#define OUT_DIM 2
#define NW      32               // nodes per block tile
#define SLOPE   0.01f

#define ST      132              // tile row stride (fp32/uint32 units)
#define WSLICE  (NW * ST)        // 4224 words = 16.9 KB

#define SSTRIDE 520              // bf16 units per s-step in A planes (512+8 pad)
#define PLANE   (8 * SSTRIDE)    // 4160 bf16 per plane

#define SCAN_B  512
#define SCAN_NB ((N_NODES + SCAN_B - 1) / SCAN_B)   // 98

typedef unsigned int uint32;
typedef __attribute__((ext_vector_type(8)))  __bf16 bf16x8v;
typedef __attribute__((ext_vector_type(16))) float  f32x16;

union BF8 { bf16x8v v; unsigned short s[8]; uint4 q; };

// weight-fragment table offsets (frag = 2 uint4: hi, lo)
#define FI_F 0        // W_in : S=16 -> 4096 frags
#define FN_F 4096     // W_nor: S=4  -> 1024
#define FA_F 5120     // W_abnor: S=4 -> 1024
#define FT_F 6144     // W_att: S=8 -> 2048
#define FU_F 8192     // W_upd: S=8 -> 2048
#define F_TOTAL 10240 // 20480 uint4 = 320 KB

__device__ __forceinline__ uint32 rne16u(uint32 u) {
    return (u + 0x7fffu + ((u >> 16) & 1u)) >> 16;
}

// pack one fp32 into (hi_bf16 << 16) | lo_bf16  (error-compensated split)
__device__ __forceinline__ uint32 pack_hl(float v) {
    uint32 uu = __float_as_uint(v);
    uint32 hh = rne16u(uu);
    float  fh = __uint_as_float(hh << 16);
    float  r  = v - fh;
    uint32 ll = rne16u(__float_as_uint(r));
    return (hh << 16) | ll;
}

// fast tanh / sigmoid via v_exp + v_rcp (~1e-7 rel err)
__device__ __forceinline__ float fast_tanh(float x) {
    float ex = __expf(2.f * x);
    return 1.f - 2.f * __builtin_amdgcn_rcpf(ex + 1.f);
}
__device__ __forceinline__ float fast_sig(float x) {
    return __builtin_amdgcn_rcpf(1.f + __expf(-x));
}

__device__ __forceinline__ void mfma3(f32x16& acc, bf16x8v ah, bf16x8v al,
                                      bf16x8v bh, bf16x8v bl) {
    acc = __builtin_amdgcn_mfma_f32_32x32x16_bf16(ah, bh, acc, 0, 0, 0);
    acc = __builtin_amdgcn_mfma_f32_32x32x16_bf16(ah, bl, acc, 0, 0, 0);
    acc = __builtin_amdgcn_mfma_f32_32x32x16_bf16(al, bh, acc, 0, 0, 0);
}

// split a float4 at (row rr, local col k) into fragment-ordered LDS planes.
// A-frag (32x32x16): slot = s*SSTRIDE + lane*8 + j, lane = rr + 32*((k>>3)&1).
__device__ __forceinline__ void stage_split4(__bf16* __restrict__ Ahi,
                                             __bf16* __restrict__ Alo,
                                             int rr, int k, float4 v) {
    int s_idx = k >> 4, jb = k & 7, lt = rr + 32 * ((k >> 3) & 1);
    int base = s_idx * SSTRIDE + lt * 8 + jb;
    float f[4] = {v.x, v.y, v.z, v.w};
    uint32 h[4], lo[4];
    #pragma unroll
    for (int j = 0; j < 4; j++) {
        uint32 uu = __float_as_uint(f[j]);
        uint32 hh = rne16u(uu);
        float  fh = __uint_as_float(hh << 16);
        float  r  = f[j] - fh;
        h[j] = hh; lo[j] = rne16u(__float_as_uint(r));
    }
    *(uint2*)(Ahi + base) = make_uint2(h[0] | (h[1] << 16), h[2] | (h[3] << 16));
    *(uint2*)(Alo + base) = make_uint2(lo[0] | (lo[1] << 16), lo[2] | (lo[3] << 16));
}

// 1-tile GEMM from pre-split planes: pure ds_read + F-load + MFMA
__device__ __forceinline__ void mfma_gemm1_pre(f32x16& acc,
        const __bf16* __restrict__ Ahi, const __bf16* __restrict__ Alo,
        int S, int sg0, const uint4* __restrict__ F, int fbase, int l, int t) {
    for (int s = 0; s < S; s++) {
        bf16x8v ah = *(const bf16x8v*)&Ahi[s * SSTRIDE + l * 8];
        bf16x8v al = *(const bf16x8v*)&Alo[s * SSTRIDE + l * 8];
        int f = fbase + ((sg0 + s) * 4 + t) * 64 + l;
        BF8 bh, bl; bh.q = F[2 * f]; bl.q = F[2 * f + 1];
        mfma3(acc, ah, al, bh.v, bl.v);
    }
}

// 1-tile GEMM from packed (hi|lo) uint32 tile: 2 b128 + 8 shift/mask unpacks
__device__ __forceinline__ void mfma_gemm1_pk(f32x16& acc, const uint32* T,
        int aoff, int S, const uint4* __restrict__ F, int fbase, int l, int t) {
    const int row = l & 31, khi = 8 * (l >> 5);
    for (int s = 0; s < S; s++) {
        int k0 = aoff + 16 * s + khi;
        uint4 qa = *(const uint4*)&T[row * ST + k0];
        uint4 qb = *(const uint4*)&T[row * ST + k0 + 4];
        BF8 ah, al;
        ah.q.x = (qa.x >> 16) | (qa.y & 0xffff0000u);
        ah.q.y = (qa.z >> 16) | (qa.w & 0xffff0000u);
        ah.q.z = (qb.x >> 16) | (qb.y & 0xffff0000u);
        ah.q.w = (qb.z >> 16) | (qb.w & 0xffff0000u);
        al.q.x = (qa.x & 0xffffu) | (qa.y << 16);
        al.q.y = (qa.z & 0xffffu) | (qa.w << 16);
        al.q.z = (qb.x & 0xffffu) | (qb.y << 16);
        al.q.w = (qb.z & 0xffffu) | (qb.w << 16);
        int f = fbase + (s * 4 + t) * 64 + l;
        BF8 bh, bl; bh.q = F[2 * f]; bl.q = F[2 * f + 1];
        mfma3(acc, ah.v, al.v, bh.v, bl.v);
    }
}

__device__ __forceinline__ uint32 pack_bf2(float x, float y) {
    return rne16u(__float_as_uint(x)) | (rne16u(__float_as_uint(y)) << 16);
}

// ---------------------------------------------------------------- degree ----
__global__ void zero_int_kernel(int* __restrict__ p, int n) {
    int i = blockIdx.x * blockDim.x + threadIdx.x;
    if (i < n) p[i] = 0;
}

__global__ void deg_ticket_kernel(const int* __restrict__ col,
                                  int* __restrict__ cnt, int* __restrict__ ticket) {
    int e = blockIdx.x * blockDim.x + threadIdx.x;
    if (e < E_EDGES) ticket[e] = atomicAdd(&cnt[col[e]], 1);
}

// ------------------------------------------------------- 3-pass fast scan ---
__device__ __forceinline__ int wave_iscan(int v, int l) {
    #pragma unroll
    for (int off = 1; off < 64; off <<= 1) {
        int t = __shfl_up(v, off, 64);
        if (l >= off) v += t;
    }
    return v;
}

__global__ __launch_bounds__(SCAN_B) void scan1_kernel(
    const int* __restrict__ cnt, int* __restrict__ row_start, int* __restrict__ bsum)
{
    __shared__ int wsum[SCAN_B / 64];
    int i = blockIdx.x * SCAN_B + threadIdx.x;
    int v = (i < N_NODES) ? cnt[i] : 0;
    int l = threadIdx.x & 63, w = threadIdx.x >> 6;
    int isc = wave_iscan(v, l);
    if (l == 63) wsum[w] = isc;
    __syncthreads();
    int wo = 0;
    #pragma unroll
    for (int k = 0; k < SCAN_B / 64; k++) wo += (k < w) ? wsum[k] : 0;
    if (i < N_NODES) row_start[i] = wo + isc - v;
    if (threadIdx.x == SCAN_B - 1) bsum[blockIdx.x] = wo + isc;
}

__global__ __launch_bounds__(128) void scan2_kernel(
    int* __restrict__ bsum, int* __restrict__ row_start)
{
    __shared__ int wsum[2];
    int i = threadIdx.x;
    int v = (i < SCAN_NB) ? bsum[i] : 0;
    int l = i & 63, w = i >> 6;
    int isc = wave_iscan(v, l);
    if (l == 63) wsum[w] = isc;
    __syncthreads();
    int wo = (w == 1) ? wsum[0] : 0;
    if (i < SCAN_NB) bsum[i] = wo + isc - v;
    if (i == SCAN_NB - 1) row_start[N_NODES] = wo + isc;
}

__global__ __launch_bounds__(SCAN_B) void scan3_kernel(
    const int* __restrict__ bsum, int* __restrict__ row_start)
{
    int i = blockIdx.x * SCAN_B + threadIdx.x;
    if (i < N_NODES) row_start[i] += bsum[blockIdx.x];
}

__global__ void fill_kernel(const int* __restrict__ ei,
                            const int* __restrict__ row_start,
                            const int* __restrict__ ticket,
                            int* __restrict__ csr_src)
{
    int e = blockIdx.x * blockDim.x + threadIdx.x;
    if (e >= E_EDGES) return;
    int j = ei[e];
    int i = ei[E_EDGES + e];
    csr_src[row_start[i] + ticket[e]] = j;
}

// ---------------------------------------------------- weight prep (split) ---
// B-frag layout (32x32x16): col = lane&31, k = 8*(lane>>5)+j.
__global__ __launch_bounds__(256) void prep_w_kernel(
    const float* __restrict__ W_in, const float* __restrict__ W_nor,
    const float* __restrict__ W_ab, const float* __restrict__ W_att,
    const float* __restrict__ W_upd,
    uint4* __restrict__ F)
{
    int idx = blockIdx.x * 256 + threadIdx.x;
    const float* W; int fbase, fi;
    if (idx < 4096)       { W = W_in;  fbase = FI_F; fi = idx; }
    else if (idx < 5120)  { W = W_nor; fbase = FN_F; fi = idx - 4096; }
    else if (idx < 6144)  { W = W_ab;  fbase = FA_F; fi = idx - 5120; }
    else if (idx < 8192)  { W = W_att; fbase = FT_F; fi = idx - 6144; }
    else if (idx < 10240) { W = W_upd; fbase = FU_F; fi = idx - 8192; }
    else return;
    int l = fi & 63, st = fi >> 6, t = st & 3, s = st >> 2;
    int k0 = 16 * s + 8 * (l >> 5);
    int c  = 32 * t + (l & 31);
    uint32 hi[8], lo[8];
    #pragma unroll
    for (int j = 0; j < 8; j++) {
        float v = W[(size_t)(k0 + j) * HID + c];
        uint32 uu = __float_as_uint(v);
        uint32 h  = rne16u(uu);
        float  fh = __uint_as_float(h << 16);
        float  r  = v - fh;
        hi[j] = h;
        lo[j] = rne16u(__float_as_uint(r));
    }
    uint4 H, L;
    H.x = hi[0] | (hi[1] << 16); H.y = hi[2] | (hi[3] << 16);
    H.z = hi[4] | (hi[5] << 16); H.w = hi[6] | (hi[7] << 16);
    L.x = lo[0] | (lo[1] << 16); L.y = lo[2] | (lo[3] << 16);
    L.z = lo[4] | (lo[5] << 16); L.w = lo[6] | (lo[7] << 16);
    int f = fbase + fi;
    F[2 * f]     = H;
    F[2 * f + 1] = L;
}

// ------------------------------------------------------------- node phase ---
// 256 threads = 4 waves per 32-node tile; wave w owns output cols 32w..32w+31.
__global__ __launch_bounds__(256, 4) void node_phase_kernel(
    const float* __restrict__ x,
    const float* __restrict__ b_in,  const float* __restrict__ b_nor,
    const float* __restrict__ b_abnor, const float* __restrict__ b_att,
    const float* __restrict__ v_att,
    const int* __restrict__ cnt,
    const uint4* __restrict__ F,
    uint32* __restrict__ u)            // [N][HID/2] packed bf16 pairs
{
    __shared__ __align__(16) float smem[WSLICE];   // 16.9 KB overlaid
    __shared__ float dinvs[NW];
    __shared__ float gpart[4][NW];
    __bf16* Ahi = (__bf16*)smem;              // padded plane (4160 bf16)
    __bf16* Alo = (__bf16*)smem + PLANE;      // second plane
    uint32* T   = (uint32*)smem;              // packed h/s tile [32][ST]

    const int tid    = threadIdx.x;
    const int w      = tid >> 6;          // tile t = w
    const int l      = tid & 63;
    const int col    = l & 31;
    const int hi     = l >> 5;
    const int wnode0 = blockIdx.x * NW;

    if (tid < NW) {
        int nd = wnode0 + tid;
        float c = (nd < N_NODES) ? (float)cnt[nd] : 0.f;
        dinvs[tid] = rsqrtf(c + 1.0f);
    }

    // ---- h = leaky_relu(x @ W_in + b_in), K=256 in two 128-halves ----
    f32x16 hacc;
    {
        float bv = b_in[32 * w + col];
        #pragma unroll
        for (int r2 = 0; r2 < 16; r2++) hacc[r2] = bv;
    }
    for (int half = 0; half < 2; half++) {
        #pragma unroll
        for (int it = 0; it < 4; it++) {           // 1024 float4 over 256 thr
            int i = it * 256 + tid;
            int rr = i >> 5, kq = i & 31, k = 4 * kq;
            int nd = wnode0 + rr; if (nd >= N_NODES) nd = N_NODES - 1;
            float4 v = *(const float4*)(x + (size_t)nd * IN_DIM + half * 128 + k);
            stage_split4(Ahi, Alo, rr, k, v);
        }
        __syncthreads();
        mfma_gemm1_pre(hacc, Ahi, Alo, 8, half * 8, F, FI_F, l, w);
        __syncthreads();   // planes consumed; safe to overwrite
    }

    // ---- lrelu(h) -> packed tile cols [32w, 32w+32) ----
    #pragma unroll
    for (int rg = 0; rg < 16; rg++) {
        int rrow = (rg & 3) + 8 * (rg >> 2) + 4 * hi;
        float v = hacc[rg];
        v = v > 0.f ? v : SLOPE * v;
        T[rrow * ST + 32 * w + col] = pack_hl(v);
    }
    __syncthreads();

    // ---- xn = h[:, :64] @ W_nor ; xa = h[:, 64:] @ W_abnor ----
    f32x16 xn, xa;
    {
        float bv = b_nor[32 * w + col];
        #pragma unroll
        for (int r2 = 0; r2 < 16; r2++) xn[r2] = bv;
    }
    mfma_gemm1_pk(xn, T, 0, 4, F, FN_F, l, w);
    {
        float bv = b_abnor[32 * w + col];
        #pragma unroll
        for (int r2 = 0; r2 < 16; r2++) xa[r2] = bv;
    }
    mfma_gemm1_pk(xa, T, HALF, 4, F, FA_F, l, w);
    __syncthreads();   // h consumed

    // ---- s = xn+xa (regs + packed tile); d = xn-xa (regs) ----
    f32x16 sv, d;
    #pragma unroll
    for (int rg = 0; rg < 16; rg++) {
        int rrow = (rg & 3) + 8 * (rg >> 2) + 4 * hi;
        sv[rg] = xn[rg] + xa[rg];
        d[rg]  = xn[rg] - xa[rg];
        T[rrow * ST + 32 * w + col] = pack_hl(sv[rg]);
    }
    __syncthreads();

    // ---- t = s @ W_att + b_att ----
    f32x16 tac;
    {
        float bv = b_att[32 * w + col];
        #pragma unroll
        for (int r2 = 0; r2 < 16; r2++) tac[r2] = bv;
    }
    mfma_gemm1_pk(tac, T, 0, 8, F, FT_F, l, w);

    // ---- alpha: per-wave partial (32 cols), cross-wave via gpart ----
    float g[16];
    {
        float vv = v_att[32 * w + col];
        #pragma unroll
        for (int rg = 0; rg < 16; rg++) g[rg] = fast_tanh(tac[rg]) * vv;
    }
    #pragma unroll
    for (int msk = 16; msk >= 1; msk >>= 1) {
        #pragma unroll
        for (int rg = 0; rg < 16; rg++) g[rg] += __shfl_xor(g[rg], msk, 64);
    }
    if (col == 0) {
        #pragma unroll
        for (int rg = 0; rg < 16; rg++) {
            int rrow = (rg & 3) + 8 * (rg >> 2) + 4 * hi;
            gpart[w][rrow] = g[rg];
        }
    }
    __syncthreads();

    float am[16];
    #pragma unroll
    for (int rg = 0; rg < 16; rg++) {
        int rrow = (rg & 3) + 8 * (rg >> 2) + 4 * hi;
        float gt = gpart[0][rrow] + gpart[1][rrow] + gpart[2][rrow] + gpart[3][rrow];
        am[rg] = fast_sig(gt) - 0.5f;
    }

    // ---- u = dinv * (0.5*s + (alpha-0.5)*d), packed bf16 pairs ----
    #pragma unroll
    for (int rg = 0; rg < 16; rg++) {
        int rrow = (rg & 3) + 8 * (rg >> 2) + 4 * hi;
        int n    = wnode0 + rrow;
        float uv = dinvs[rrow] * (0.5f * sv[rg] + am[rg] * d[rg]);
        float pv = __shfl_xor(uv, 1, 64);
        if (((l & 1) == 0) && n < N_NODES) {
            u[(size_t)n * (HID / 2) + 16 * w + (col >> 1)] = pack_bf2(uv, pv);
        }
    }
}

// ----------------------------------------------- fused gather + final phase ---
// 256 threads = 4 waves per 32-node tile. Wave w gathers nodes 8w..8w+7 from
// u via CSR (serial per node, predicated 8-batches), applies dinv, and stages
// the aggregated rows DIRECTLY into the MFMA A-planes. Then FU MFMA + cls.
// launch_bounds (256,8): kernel fits 32-64 VGPR -> 8 waves/SIMD resident.
__global__ __launch_bounds__(256, 8) void final_fused_kernel(
    const int* __restrict__ row_start, const int* __restrict__ csr_src,
    const uint32* __restrict__ u, const int* __restrict__ cnt,
    const float* __restrict__ b_upd,
    const float* __restrict__ W_cls, const float* __restrict__ b_cls,
    const uint4* __restrict__ F,
    float* __restrict__ out)
{
    __shared__ __align__(16) float smem[WSLICE];
    __bf16* Ahi = (__bf16*)smem;
    __bf16* Alo = (__bf16*)smem + PLANE;

    const int tid    = threadIdx.x;
    const int w      = tid >> 6;
    const int l      = tid & 63;
    const int col    = l & 31;
    const int hi     = l >> 5;
    const int wnode0 = blockIdx.x * NW;

    const size_t RW = HID / 2;
    // plane slot for this lane's pair (cols k=2l, 2l+1); same slot for all 8 rows
    const int kk   = 2 * l;
    const int sidx = kk >> 4, jj = kk & 7, ltb = 32 * ((kk >> 3) & 1);

    for (int q = 0; q < 8; q++) {
        int rr = 8 * w + q;
        int nd = wnode0 + rr; if (nd >= N_NODES) nd = N_NODES - 1;

        uint32 v = u[(size_t)nd * RW + l];
        float sx = __uint_as_float(v << 16);
        float sy = __uint_as_float(v & 0xffff0000u);

        int b = row_start[nd], e = row_start[nd + 1];
        for (int p = b; p < e; p += 8) {
            int idx[8];
            #pragma unroll
            for (int qq = 0; qq < 8; qq++) {
                int a = p + qq; if (a > e - 1) a = e - 1;
                idx[qq] = csr_src[a];
            }
            uint32 vv[8];
            #pragma unroll
            for (int qq = 0; qq < 8; qq++) vv[qq] = u[(size_t)idx[qq] * RW + l];
            #pragma unroll
            for (int qq = 0; qq < 8; qq++) {
                if (p + qq < e) {
                    sx += __uint_as_float(vv[qq] << 16);
                    sy += __uint_as_float(vv[qq] & 0xffff0000u);
                }
            }
        }
        float dv = rsqrtf((float)cnt[nd] + 1.0f);
        sx *= dv; sy *= dv;

        // split-stage this pair into the A-planes
        uint32 px = pack_hl(sx), py = pack_hl(sy);
        int base = sidx * SSTRIDE + (rr + ltb) * 8 + jj;
        *(uint32*)&Ahi[base] = (px >> 16) | (py & 0xffff0000u);
        *(uint32*)&Alo[base] = (px & 0xffffu) | (py << 16);
    }
    __syncthreads();

    f32x16 up;
    {
        float bv = b_upd[32 * w + col];
        #pragma unroll
        for (int r2 = 0; r2 < 16; r2++) up[r2] = bv;
    }
    mfma_gemm1_pre(up, Ahi, Alo, 8, 0, F, FU_F, l, w);
    __syncthreads();   // planes consumed before overwrite

    // lrelu -> fp32 tile cols [32w, 32w+32)
    float* B = smem;
    #pragma unroll
    for (int rg = 0; rg < 16; rg++) {
        int rrow = (rg & 3) + 8 * (rg >> 2) + 4 * hi;
        float v = up[rg];
        B[rrow * ST + 32 * w + col] = v > 0.f ? v : SLOPE * v;
    }
    __syncthreads();

    // classifier: tid = n*8 + o*4 + c ; 4 lanes per (node,out), shfl-reduce
    {
        int n = tid >> 3, o = (tid >> 2) & 1, c = tid & 3;
        float s = 0.f;
        int k0 = c * 32;
        for (int k = k0; k < k0 + 32; k++)
            s = fmaf(B[n * ST + k], W_cls[k * OUT_DIM + o], s);
        s += __shfl_xor(s, 1, 64);
        s += __shfl_xor(s, 2, 64);
        if (c == 0 && wnode0 + n < N_NODES) {
            out[(size_t)(wnode0 + n) * OUT_DIM + o] = s + b_cls[o];
        }
    }
}

// ------------------------------------------------------------------ launch --
extern "C" void kernel_launch(void* const* d_in, const int* in_sizes, int n_in,
                              void* d_out, int out_size, void* d_ws, size_t ws_size,
                              hipStream_t stream)
{
    const float* x       = (const float*)d_in[0];
    const int*   ei      = (const int*)  d_in[1];   // [2, E] int32
    const float* W_in    = (const float*)d_in[2];
    const float* b_in    = (const float*)d_in[3];
    const float* W_nor   = (const float*)d_in[4];
    const float* b_nor   = (const float*)d_in[5];
    const float* W_abnor = (const float*)d_in[6];
    const float* b_abnor = (const float*)d_in[7];
    const float* W_att   = (const float*)d_in[8];
    const float* b_att   = (const float*)d_in[9];
    const float* v_att   = (const float*)d_in[10];
    const float* W_upd   = (const float*)d_in[11];
    const float* b_upd   = (const float*)d_in[12];
    const float* W_cls   = (const float*)d_in[13];
    const float* b_cls   = (const float*)d_in[14];
    float* out = (float*)d_out;

    // ws: cnt[N] | row_start[N+1] | bsum[128] | csr_src[E] | ticket[E]
    //     | u_bf16[N*64 uints] | F[20480 uint4]   (~20 MB)
    char* base = (char*)d_ws;
    int*  cnt       = (int*)base;
    int*  row_start = cnt + N_NODES;
    int*  bsum      = row_start + (N_NODES + 1);
    int*  csr_src   = bsum + 128;
    int*  ticket    = csr_src + E_EDGES;
    size_t off_u    = (((size_t)(2 * N_NODES + 129 + 2 * E_EDGES)) * 4 + 63) & ~(size_t)63;
    uint32* u       = (uint32*)(base + off_u);
    size_t off_f    = (off_u + (size_t)N_NODES * (HID / 2) * 4 + 63) & ~(size_t)63;
    uint4* F        = (uint4*)(base + off_f);

    const int nblk = (N_NODES + NW - 1) / NW;   // 1563

    zero_int_kernel<<<(N_NODES + 255) / 256, 256, 0, stream>>>(cnt, N_NODES);
    deg_ticket_kernel<<<(E_EDGES + 255) / 256, 256, 0, stream>>>(ei + E_EDGES, cnt, ticket);
    scan1_kernel<<<SCAN_NB, SCAN_B, 0, stream>>>(cnt, row_start, bsum);
    scan2_kernel<<<1, 128, 0, stream>>>(bsum, row_start);
    scan3_kernel<<<SCAN_NB, SCAN_B, 0, stream>>>(bsum, row_start);
    fill_kernel<<<(E_EDGES + 255) / 256, 256, 0, stream>>>(ei, row_start, ticket, csr_src);
    prep_w_kernel<<<F_TOTAL / 256, 256, 0, stream>>>(W_in, W_nor, W_abnor, W_att, W_upd, F);
    node_phase_kernel<<<nblk, 256, 0, stream>>>(
        x, b_in, b_nor, b_abnor, b_att, v_att, cnt, F, u);
    final_fused_kernel<<<nblk, 256, 0, stream>>>(
        row_start, csr_src, u, cnt, b_upd, W_cls, b_cls, F, out);
}

// Round 21
// 151.841 us; speedup vs baseline: 1.3005x; 1.0469x over previous
//
#include <hip/hip_runtime.h>

#define N_NODES 50000
#define E_EDGES 800000
#define IN_DIM  256
#define HID     128
#define HALF    64
#define OUT_DIM 2
#define NW      32               // nodes per block tile
#define SLOPE   0.01f

#define ST      132              // tile row stride (fp32/uint32 units)
#define WSLICE  (NW * ST)        // 4224 words = 16.9 KB

#define SSTRIDE 520              // bf16 units per s-step in A planes (512+8 pad)
#define PLANE   (8 * SSTRIDE)    // 4160 bf16 per plane

#define SCAN_B  512
#define SCAN_NB ((N_NODES + SCAN_B - 1) / SCAN_B)   // 98

typedef unsigned int uint32;
typedef __attribute__((ext_vector_type(8)))  __bf16 bf16x8v;
typedef __attribute__((ext_vector_type(16))) float  f32x16;

union BF8 { bf16x8v v; unsigned short s[8]; uint4 q; };

// weight-fragment table offsets (frag = 2 uint4: hi, lo)
#define FI_F 0        // W_in : S=16 -> 4096 frags
#define FN_F 4096     // W_nor: S=4  -> 1024
#define FA_F 5120     // W_abnor: S=4 -> 1024
#define FT_F 6144     // W_att: S=8 -> 2048
#define FU_F 8192     // W_upd: S=8 -> 2048
#define F_TOTAL 10240 // 20480 uint4 = 320 KB

__device__ __forceinline__ uint32 rne16u(uint32 u) {
    return (u + 0x7fffu + ((u >> 16) & 1u)) >> 16;
}

// pack one fp32 into (hi_bf16 << 16) | lo_bf16  (error-compensated split)
__device__ __forceinline__ uint32 pack_hl(float v) {
    uint32 uu = __float_as_uint(v);
    uint32 hh = rne16u(uu);
    float  fh = __uint_as_float(hh << 16);
    float  r  = v - fh;
    uint32 ll = rne16u(__float_as_uint(r));
    return (hh << 16) | ll;
}

// fast tanh / sigmoid via v_exp + v_rcp (~1e-7 rel err)
__device__ __forceinline__ float fast_tanh(float x) {
    float ex = __expf(2.f * x);
    return 1.f - 2.f * __builtin_amdgcn_rcpf(ex + 1.f);
}
__device__ __forceinline__ float fast_sig(float x) {
    return __builtin_amdgcn_rcpf(1.f + __expf(-x));
}

__device__ __forceinline__ void mfma3(f32x16& acc, bf16x8v ah, bf16x8v al,
                                      bf16x8v bh, bf16x8v bl) {
    acc = __builtin_amdgcn_mfma_f32_32x32x16_bf16(ah, bh, acc, 0, 0, 0);
    acc = __builtin_amdgcn_mfma_f32_32x32x16_bf16(ah, bl, acc, 0, 0, 0);
    acc = __builtin_amdgcn_mfma_f32_32x32x16_bf16(al, bh, acc, 0, 0, 0);
}

// split a float4 at (row rr, local col k) into fragment-ordered LDS planes.
// A-frag (32x32x16): slot = s*SSTRIDE + lane*8 + j, lane = rr + 32*((k>>3)&1).
__device__ __forceinline__ void stage_split4(__bf16* __restrict__ Ahi,
                                             __bf16* __restrict__ Alo,
                                             int rr, int k, float4 v) {
    int s_idx = k >> 4, jb = k & 7, lt = rr + 32 * ((k >> 3) & 1);
    int base = s_idx * SSTRIDE + lt * 8 + jb;
    float f[4] = {v.x, v.y, v.z, v.w};
    uint32 h[4], lo[4];
    #pragma unroll
    for (int j = 0; j < 4; j++) {
        uint32 uu = __float_as_uint(f[j]);
        uint32 hh = rne16u(uu);
        float  fh = __uint_as_float(hh << 16);
        float  r  = f[j] - fh;
        h[j] = hh; lo[j] = rne16u(__float_as_uint(r));
    }
    *(uint2*)(Ahi + base) = make_uint2(h[0] | (h[1] << 16), h[2] | (h[3] << 16));
    *(uint2*)(Alo + base) = make_uint2(lo[0] | (lo[1] << 16), lo[2] | (lo[3] << 16));
}

// 1-tile GEMM from pre-split planes: pure ds_read + F-load + MFMA
__device__ __forceinline__ void mfma_gemm1_pre(f32x16& acc,
        const __bf16* __restrict__ Ahi, const __bf16* __restrict__ Alo,
        int S, int sg0, const uint4* __restrict__ F, int fbase, int l, int t) {
    for (int s = 0; s < S; s++) {
        bf16x8v ah = *(const bf16x8v*)&Ahi[s * SSTRIDE + l * 8];
        bf16x8v al = *(const bf16x8v*)&Alo[s * SSTRIDE + l * 8];
        int f = fbase + ((sg0 + s) * 4 + t) * 64 + l;
        BF8 bh, bl; bh.q = F[2 * f]; bl.q = F[2 * f + 1];
        mfma3(acc, ah, al, bh.v, bl.v);
    }
}

// 1-tile GEMM from packed (hi|lo) uint32 tile: 2 b128 + 8 shift/mask unpacks
__device__ __forceinline__ void mfma_gemm1_pk(f32x16& acc, const uint32* T,
        int aoff, int S, const uint4* __restrict__ F, int fbase, int l, int t) {
    const int row = l & 31, khi = 8 * (l >> 5);
    for (int s = 0; s < S; s++) {
        int k0 = aoff + 16 * s + khi;
        uint4 qa = *(const uint4*)&T[row * ST + k0];
        uint4 qb = *(const uint4*)&T[row * ST + k0 + 4];
        BF8 ah, al;
        ah.q.x = (qa.x >> 16) | (qa.y & 0xffff0000u);
        ah.q.y = (qa.z >> 16) | (qa.w & 0xffff0000u);
        ah.q.z = (qb.x >> 16) | (qb.y & 0xffff0000u);
        ah.q.w = (qb.z >> 16) | (qb.w & 0xffff0000u);
        al.q.x = (qa.x & 0xffffu) | (qa.y << 16);
        al.q.y = (qa.z & 0xffffu) | (qa.w << 16);
        al.q.z = (qb.x & 0xffffu) | (qb.y << 16);
        al.q.w = (qb.z & 0xffffu) | (qb.w << 16);
        int f = fbase + (s * 4 + t) * 64 + l;
        BF8 bh, bl; bh.q = F[2 * f]; bl.q = F[2 * f + 1];
        mfma3(acc, ah.v, al.v, bh.v, bl.v);
    }
}

__device__ __forceinline__ uint32 pack_bf2(float x, float y) {
    return rne16u(__float_as_uint(x)) | (rne16u(__float_as_uint(y)) << 16);
}

// ---------------------------------------------------------------- degree ----
__global__ void deg_ticket_kernel(const int* __restrict__ col,
                                  int* __restrict__ cnt, int* __restrict__ ticket) {
    int e = blockIdx.x * blockDim.x + threadIdx.x;
    if (e < E_EDGES) ticket[e] = atomicAdd(&cnt[col[e]], 1);
}

// ------------------------------------------------------- 3-pass fast scan ---
__device__ __forceinline__ int wave_iscan(int v, int l) {
    #pragma unroll
    for (int off = 1; off < 64; off <<= 1) {
        int t = __shfl_up(v, off, 64);
        if (l >= off) v += t;
    }
    return v;
}

__global__ __launch_bounds__(SCAN_B) void scan1_kernel(
    const int* __restrict__ cnt, int* __restrict__ row_start, int* __restrict__ bsum)
{
    __shared__ int wsum[SCAN_B / 64];
    int i = blockIdx.x * SCAN_B + threadIdx.x;
    int v = (i < N_NODES) ? cnt[i] : 0;
    int l = threadIdx.x & 63, w = threadIdx.x >> 6;
    int isc = wave_iscan(v, l);
    if (l == 63) wsum[w] = isc;
    __syncthreads();
    int wo = 0;
    #pragma unroll
    for (int k = 0; k < SCAN_B / 64; k++) wo += (k < w) ? wsum[k] : 0;
    if (i < N_NODES) row_start[i] = wo + isc - v;
    if (threadIdx.x == SCAN_B - 1) bsum[blockIdx.x] = wo + isc;
}

__global__ __launch_bounds__(128) void scan2_kernel(
    int* __restrict__ bsum, int* __restrict__ row_start)
{
    __shared__ int wsum[2];
    int i = threadIdx.x;
    int v = (i < SCAN_NB) ? bsum[i] : 0;
    int l = i & 63, w = i >> 6;
    int isc = wave_iscan(v, l);
    if (l == 63) wsum[w] = isc;
    __syncthreads();
    int wo = (w == 1) ? wsum[0] : 0;
    if (i < SCAN_NB) bsum[i] = wo + isc - v;
    if (i == SCAN_NB - 1) row_start[N_NODES] = wo + isc;
}

__global__ __launch_bounds__(SCAN_B) void scan3_kernel(
    const int* __restrict__ bsum, int* __restrict__ row_start)
{
    int i = blockIdx.x * SCAN_B + threadIdx.x;
    if (i < N_NODES) row_start[i] += bsum[blockIdx.x];
}

__global__ void fill_kernel(const int* __restrict__ ei,
                            const int* __restrict__ row_start,
                            const int* __restrict__ ticket,
                            int* __restrict__ csr_src)
{
    int e = blockIdx.x * blockDim.x + threadIdx.x;
    if (e >= E_EDGES) return;
    int j = ei[e];
    int i = ei[E_EDGES + e];
    csr_src[row_start[i] + ticket[e]] = j;
}

// ---------------------------------------------------- weight prep (split) ---
// B-frag layout (32x32x16): col = lane&31, k = 8*(lane>>5)+j.
__global__ __launch_bounds__(256) void prep_w_kernel(
    const float* __restrict__ W_in, const float* __restrict__ W_nor,
    const float* __restrict__ W_ab, const float* __restrict__ W_att,
    const float* __restrict__ W_upd,
    uint4* __restrict__ F)
{
    int idx = blockIdx.x * 256 + threadIdx.x;
    const float* W; int fbase, fi;
    if (idx < 4096)       { W = W_in;  fbase = FI_F; fi = idx; }
    else if (idx < 5120)  { W = W_nor; fbase = FN_F; fi = idx - 4096; }
    else if (idx < 6144)  { W = W_ab;  fbase = FA_F; fi = idx - 5120; }
    else if (idx < 8192)  { W = W_att; fbase = FT_F; fi = idx - 6144; }
    else if (idx < 10240) { W = W_upd; fbase = FU_F; fi = idx - 8192; }
    else return;
    int l = fi & 63, st = fi >> 6, t = st & 3, s = st >> 2;
    int k0 = 16 * s + 8 * (l >> 5);
    int c  = 32 * t + (l & 31);
    uint32 hi[8], lo[8];
    #pragma unroll
    for (int j = 0; j < 8; j++) {
        float v = W[(size_t)(k0 + j) * HID + c];
        uint32 uu = __float_as_uint(v);
        uint32 h  = rne16u(uu);
        float  fh = __uint_as_float(h << 16);
        float  r  = v - fh;
        hi[j] = h;
        lo[j] = rne16u(__float_as_uint(r));
    }
    uint4 H, L;
    H.x = hi[0] | (hi[1] << 16); H.y = hi[2] | (hi[3] << 16);
    H.z = hi[4] | (hi[5] << 16); H.w = hi[6] | (hi[7] << 16);
    L.x = lo[0] | (lo[1] << 16); L.y = lo[2] | (lo[3] << 16);
    L.z = lo[4] | (lo[5] << 16); L.w = lo[6] | (lo[7] << 16);
    int f = fbase + fi;
    F[2 * f]     = H;
    F[2 * f + 1] = L;
}

// ------------------------------------------------------------- node phase ---
// 256 threads = 4 waves per 32-node tile; wave w owns output cols 32w..32w+31.
__global__ __launch_bounds__(256, 4) void node_phase_kernel(
    const float* __restrict__ x,
    const float* __restrict__ b_in,  const float* __restrict__ b_nor,
    const float* __restrict__ b_abnor, const float* __restrict__ b_att,
    const float* __restrict__ v_att,
    const int* __restrict__ cnt,
    const uint4* __restrict__ F,
    uint32* __restrict__ u)            // [N][HID/2] packed bf16 pairs
{
    __shared__ __align__(16) float smem[WSLICE];   // 16.9 KB overlaid
    __shared__ float dinvs[NW];
    __shared__ float gpart[4][NW];
    __bf16* Ahi = (__bf16*)smem;              // padded plane (4160 bf16)
    __bf16* Alo = (__bf16*)smem + PLANE;      // second plane
    uint32* T   = (uint32*)smem;              // packed h/s tile [32][ST]

    const int tid    = threadIdx.x;
    const int w      = tid >> 6;          // tile t = w
    const int l      = tid & 63;
    const int col    = l & 31;
    const int hi     = l >> 5;
    const int wnode0 = blockIdx.x * NW;

    if (tid < NW) {
        int nd = wnode0 + tid;
        float c = (nd < N_NODES) ? (float)cnt[nd] : 0.f;
        dinvs[tid] = rsqrtf(c + 1.0f);
    }

    // ---- h = leaky_relu(x @ W_in + b_in), K=256 in two 128-halves ----
    f32x16 hacc;
    {
        float bv = b_in[32 * w + col];
        #pragma unroll
        for (int r2 = 0; r2 < 16; r2++) hacc[r2] = bv;
    }
    for (int half = 0; half < 2; half++) {
        #pragma unroll
        for (int it = 0; it < 4; it++) {           // 1024 float4 over 256 thr
            int i = it * 256 + tid;
            int rr = i >> 5, kq = i & 31, k = 4 * kq;
            int nd = wnode0 + rr; if (nd >= N_NODES) nd = N_NODES - 1;
            float4 v = *(const float4*)(x + (size_t)nd * IN_DIM + half * 128 + k);
            stage_split4(Ahi, Alo, rr, k, v);
        }
        __syncthreads();
        mfma_gemm1_pre(hacc, Ahi, Alo, 8, half * 8, F, FI_F, l, w);
        __syncthreads();   // planes consumed; safe to overwrite
    }

    // ---- lrelu(h) -> packed tile cols [32w, 32w+32) ----
    #pragma unroll
    for (int rg = 0; rg < 16; rg++) {
        int rrow = (rg & 3) + 8 * (rg >> 2) + 4 * hi;
        float v = hacc[rg];
        v = v > 0.f ? v : SLOPE * v;
        T[rrow * ST + 32 * w + col] = pack_hl(v);
    }
    __syncthreads();

    // ---- xn = h[:, :64] @ W_nor ; xa = h[:, 64:] @ W_abnor ----
    f32x16 xn, xa;
    {
        float bv = b_nor[32 * w + col];
        #pragma unroll
        for (int r2 = 0; r2 < 16; r2++) xn[r2] = bv;
    }
    mfma_gemm1_pk(xn, T, 0, 4, F, FN_F, l, w);
    {
        float bv = b_abnor[32 * w + col];
        #pragma unroll
        for (int r2 = 0; r2 < 16; r2++) xa[r2] = bv;
    }
    mfma_gemm1_pk(xa, T, HALF, 4, F, FA_F, l, w);
    __syncthreads();   // h consumed

    // ---- s = xn+xa (regs + packed tile); d = xn-xa (regs) ----
    f32x16 sv, d;
    #pragma unroll
    for (int rg = 0; rg < 16; rg++) {
        int rrow = (rg & 3) + 8 * (rg >> 2) + 4 * hi;
        sv[rg] = xn[rg] + xa[rg];
        d[rg]  = xn[rg] - xa[rg];
        T[rrow * ST + 32 * w + col] = pack_hl(sv[rg]);
    }
    __syncthreads();

    // ---- t = s @ W_att + b_att ----
    f32x16 tac;
    {
        float bv = b_att[32 * w + col];
        #pragma unroll
        for (int r2 = 0; r2 < 16; r2++) tac[r2] = bv;
    }
    mfma_gemm1_pk(tac, T, 0, 8, F, FT_F, l, w);

    // ---- alpha: per-wave partial (32 cols), cross-wave via gpart ----
    float g[16];
    {
        float vv = v_att[32 * w + col];
        #pragma unroll
        for (int rg = 0; rg < 16; rg++) g[rg] = fast_tanh(tac[rg]) * vv;
    }
    #pragma unroll
    for (int msk = 16; msk >= 1; msk >>= 1) {
        #pragma unroll
        for (int rg = 0; rg < 16; rg++) g[rg] += __shfl_xor(g[rg], msk, 64);
    }
    if (col == 0) {
        #pragma unroll
        for (int rg = 0; rg < 16; rg++) {
            int rrow = (rg & 3) + 8 * (rg >> 2) + 4 * hi;
            gpart[w][rrow] = g[rg];
        }
    }
    __syncthreads();

    float am[16];
    #pragma unroll
    for (int rg = 0; rg < 16; rg++) {
        int rrow = (rg & 3) + 8 * (rg >> 2) + 4 * hi;
        float gt = gpart[0][rrow] + gpart[1][rrow] + gpart[2][rrow] + gpart[3][rrow];
        am[rg] = fast_sig(gt) - 0.5f;
    }

    // ---- u = dinv * (0.5*s + (alpha-0.5)*d), packed bf16 pairs ----
    #pragma unroll
    for (int rg = 0; rg < 16; rg++) {
        int rrow = (rg & 3) + 8 * (rg >> 2) + 4 * hi;
        int n    = wnode0 + rrow;
        float uv = dinvs[rrow] * (0.5f * sv[rg] + am[rg] * d[rg]);
        float pv = __shfl_xor(uv, 1, 64);
        if (((l & 1) == 0) && n < N_NODES) {
            u[(size_t)n * (HID / 2) + 16 * w + (col >> 1)] = pack_bf2(uv, pv);
        }
    }
}

// ----------------------------------------------- fused gather + final phase ---
// 256 threads = 4 waves per 32-node tile. Wave w gathers nodes 8w..8w+7 from
// u via CSR: full 8-batches with NO clamp/predication, one predicated tail.
// 32-bit u addressing (row = 64 uints). Then dinv, split-stage into A-planes,
// FU MFMA (tile t=w) + classifier.
__global__ __launch_bounds__(256, 8) void final_fused_kernel(
    const int* __restrict__ row_start, const int* __restrict__ csr_src,
    const uint32* __restrict__ u, const int* __restrict__ cnt,
    const float* __restrict__ b_upd,
    const float* __restrict__ W_cls, const float* __restrict__ b_cls,
    const uint4* __restrict__ F,
    float* __restrict__ out)
{
    __shared__ __align__(16) float smem[WSLICE];
    __bf16* Ahi = (__bf16*)smem;
    __bf16* Alo = (__bf16*)smem + PLANE;

    const int tid    = threadIdx.x;
    const int w      = tid >> 6;
    const int l      = tid & 63;
    const int col    = l & 31;
    const int hi     = l >> 5;
    const int wnode0 = blockIdx.x * NW;

    // plane slot for this lane's pair (cols k=2l, 2l+1); same slot for all 8 rows
    const int kk   = 2 * l;
    const int sidx = kk >> 4, jj = kk & 7, ltb = 32 * ((kk >> 3) & 1);

    for (int q = 0; q < 8; q++) {
        int rr = 8 * w + q;
        int nd = wnode0 + rr; if (nd >= N_NODES) nd = N_NODES - 1;

        uint32 v = u[((unsigned)nd << 6) + l];
        float sx = __uint_as_float(v << 16);
        float sy = __uint_as_float(v & 0xffff0000u);

        int b = row_start[nd], e = row_start[nd + 1];
        int nfull = (e - b) >> 3;
        int p = b;
        for (int fb = 0; fb < nfull; fb++, p += 8) {
            int idx[8];
            #pragma unroll
            for (int qq = 0; qq < 8; qq++) idx[qq] = csr_src[p + qq];
            uint32 vv[8];
            #pragma unroll
            for (int qq = 0; qq < 8; qq++) vv[qq] = u[((unsigned)idx[qq] << 6) + l];
            #pragma unroll
            for (int qq = 0; qq < 8; qq++) {
                sx += __uint_as_float(vv[qq] << 16);
                sy += __uint_as_float(vv[qq] & 0xffff0000u);
            }
        }
        if (p < e) {   // single predicated tail batch
            int idx[8];
            #pragma unroll
            for (int qq = 0; qq < 8; qq++) {
                int a = p + qq; if (a > e - 1) a = e - 1;
                idx[qq] = csr_src[a];
            }
            uint32 vv[8];
            #pragma unroll
            for (int qq = 0; qq < 8; qq++) vv[qq] = u[((unsigned)idx[qq] << 6) + l];
            #pragma unroll
            for (int qq = 0; qq < 8; qq++) {
                if (p + qq < e) {
                    sx += __uint_as_float(vv[qq] << 16);
                    sy += __uint_as_float(vv[qq] & 0xffff0000u);
                }
            }
        }
        float dv = rsqrtf((float)cnt[nd] + 1.0f);
        sx *= dv; sy *= dv;

        // split-stage this pair into the A-planes
        uint32 px = pack_hl(sx), py = pack_hl(sy);
        int base = sidx * SSTRIDE + (rr + ltb) * 8 + jj;
        *(uint32*)&Ahi[base] = (px >> 16) | (py & 0xffff0000u);
        *(uint32*)&Alo[base] = (px & 0xffffu) | (py << 16);
    }
    __syncthreads();

    f32x16 up;
    {
        float bv = b_upd[32 * w + col];
        #pragma unroll
        for (int r2 = 0; r2 < 16; r2++) up[r2] = bv;
    }
    mfma_gemm1_pre(up, Ahi, Alo, 8, 0, F, FU_F, l, w);
    __syncthreads();   // planes consumed before overwrite

    // lrelu -> fp32 tile cols [32w, 32w+32)
    float* B = smem;
    #pragma unroll
    for (int rg = 0; rg < 16; rg++) {
        int rrow = (rg & 3) + 8 * (rg >> 2) + 4 * hi;
        float v = up[rg];
        B[rrow * ST + 32 * w + col] = v > 0.f ? v : SLOPE * v;
    }
    __syncthreads();

    // classifier: tid = n*8 + o*4 + c ; 4 lanes per (node,out), shfl-reduce
    {
        int n = tid >> 3, o = (tid >> 2) & 1, c = tid & 3;
        float s = 0.f;
        int k0 = c * 32;
        for (int k = k0; k < k0 + 32; k++)
            s = fmaf(B[n * ST + k], W_cls[k * OUT_DIM + o], s);
        s += __shfl_xor(s, 1, 64);
        s += __shfl_xor(s, 2, 64);
        if (c == 0 && wnode0 + n < N_NODES) {
            out[(size_t)(wnode0 + n) * OUT_DIM + o] = s + b_cls[o];
        }
    }
}

// ------------------------------------------------------------------ launch --
extern "C" void kernel_launch(void* const* d_in, const int* in_sizes, int n_in,
                              void* d_out, int out_size, void* d_ws, size_t ws_size,
                              hipStream_t stream)
{
    const float* x       = (const float*)d_in[0];
    const int*   ei      = (const int*)  d_in[1];   // [2, E] int32
    const float* W_in    = (const float*)d_in[2];
    const float* b_in    = (const float*)d_in[3];
    const float* W_nor   = (const float*)d_in[4];
    const float* b_nor   = (const float*)d_in[5];
    const float* W_abnor = (const float*)d_in[6];
    const float* b_abnor = (const float*)d_in[7];
    const float* W_att   = (const float*)d_in[8];
    const float* b_att   = (const float*)d_in[9];
    const float* v_att   = (const float*)d_in[10];
    const float* W_upd   = (const float*)d_in[11];
    const float* b_upd   = (const float*)d_in[12];
    const float* W_cls   = (const float*)d_in[13];
    const float* b_cls   = (const float*)d_in[14];
    float* out = (float*)d_out;

    // ws: cnt[N] | row_start[N+1] | bsum[128] | csr_src[E] | ticket[E]
    //     | u_bf16[N*64 uints] | F[20480 uint4]   (~20 MB)
    char* base = (char*)d_ws;
    int*  cnt       = (int*)base;
    int*  row_start = cnt + N_NODES;
    int*  bsum      = row_start + (N_NODES + 1);
    int*  csr_src   = bsum + 128;
    int*  ticket    = csr_src + E_EDGES;
    size_t off_u    = (((size_t)(2 * N_NODES + 129 + 2 * E_EDGES)) * 4 + 63) & ~(size_t)63;
    uint32* u       = (uint32*)(base + off_u);
    size_t off_f    = (off_u + (size_t)N_NODES * (HID / 2) * 4 + 63) & ~(size_t)63;
    uint4* F        = (uint4*)(base + off_f);

    const int nblk = (N_NODES + NW - 1) / NW;   // 1563

    hipMemsetAsync(cnt, 0, (size_t)N_NODES * sizeof(int), stream);
    deg_ticket_kernel<<<(E_EDGES + 255) / 256, 256, 0, stream>>>(ei + E_EDGES, cnt, ticket);
    scan1_kernel<<<SCAN_NB, SCAN_B, 0, stream>>>(cnt, row_start, bsum);
    scan2_kernel<<<1, 128, 0, stream>>>(bsum, row_start);
    scan3_kernel<<<SCAN_NB, SCAN_B, 0, stream>>>(bsum, row_start);
    fill_kernel<<<(E_EDGES + 255) / 256, 256, 0, stream>>>(ei, row_start, ticket, csr_src);
    prep_w_kernel<<<F_TOTAL / 256, 256, 0, stream>>>(W_in, W_nor, W_abnor, W_att, W_upd, F);
    node_phase_kernel<<<nblk, 256, 0, stream>>>(
        x, b_in, b_nor, b_abnor, b_att, v_att, cnt, F, u);
    final_fused_kernel<<<nblk, 256, 0, stream>>>(
        row_start, csr_src, u, cnt, b_upd, W_cls, b_cls, F, out);
}